// Round 5
// baseline (526.187 us; speedup 1.0000x reference)
//
#include <hip/hip_runtime.h>
#include <math.h>

#define H 28
#define N 784
#define B 32
#define T 25
#define NPAD 1024
#define CH 16
#define MEDGE 1536
#define NBATCH 192
#define NSLOT 13   // ceil(784/64)

// ---- numpy linspace replication (float64) ----
__device__ __forceinline__ double coord_r(int i) {
    if (i == H - 1) return 0.0;
    return 224.0 + (double)i * ((0.0 - 224.0) / 27.0);
}
__device__ __forceinline__ double coord_c(int j) {
    if (j == H - 1) return 224.0;
    return (double)j * (224.0 / 27.0);
}

// ============================================================
// K1: per-row sort by u32 key (int_d2<<10 | j).
// ============================================================
__global__ void sort_d2_kernel(float* __restrict__ d2s_t,
                               unsigned short* __restrict__ sidx_t) {
    __shared__ unsigned key[NPAD];
    const int i = blockIdx.x, tid = threadIdx.x;
    const int ri = i / H, ci = i % H;
    for (int j = tid; j < NPAD; j += 256) {
        if (j < N) {
            int dr = ri - j / H, dc = ci - j % H;
            key[j] = ((unsigned)(dr * dr + dc * dc) << 10) | (unsigned)j;
        } else {
            key[j] = 0xFFFFFFFFu;
        }
    }
    __syncthreads();
    for (int k = 2; k <= NPAD; k <<= 1) {
        for (int j = k >> 1; j > 0; j >>= 1) {
            for (int a = tid; a < NPAD; a += 256) {
                int b = a ^ j;
                if (b > a) {
                    unsigned ka = key[a], kb = key[b];
                    if ((ka > kb) == ((a & k) == 0)) { key[a] = kb; key[b] = ka; }
                }
            }
            __syncthreads();
        }
    }
    const double rri = coord_r(ri), cci = coord_c(ci);
    for (int j = tid; j < N; j += 256) {
        int jj = (int)(key[j] & 1023u);
        double dr = rri - coord_r(jj / H);
        double dc = cci - coord_c(jj % H);
        d2s_t[j * N + i]  = (float)(dr * dr + dc * dc);
        sidx_t[j * N + i] = (unsigned short)jj;
    }
}

// ============================================================
// K2: DTM. 1024 threads, one sorted-walk per thread, early exit.
// ============================================================
__global__ __launch_bounds__(1024) void dtm_kernel(
        const float* __restrict__ x,
        const float* __restrict__ d2s_t,
        const unsigned short* __restrict__ sidx_t,
        float* __restrict__ fv_g) {
    __shared__ float lw[N];
    __shared__ float red[1024];
    const int prob = blockIdx.x;
    const int b  = prob & 31;
    const int mi = prob >> 5;
    const float m0 = mi ? 0.2f : 0.05f;
    const int tid = threadIdx.x;
    float s = 0.f;
    if (tid < N) { float v = x[b * N + tid]; lw[tid] = v; s = v; }
    red[tid] = s;
    __syncthreads();
    for (int off = 512; off > 0; off >>= 1) {
        if (tid < off) red[tid] += red[tid + off];
        __syncthreads();
    }
    const float m0W = m0 * red[0];
    if (tid < N) {
        const int i = tid;
        float cum = 0.f, acc = 0.f;
        for (int k0 = 0; k0 < N; k0 += CH) {
            float d2c[CH]; int idc[CH];
            #pragma unroll
            for (int c = 0; c < CH; ++c) {
                d2c[c] = d2s_t[(k0 + c) * N + i];
                idc[c] = sidx_t[(k0 + c) * N + i];
            }
            float swc[CH];
            #pragma unroll
            for (int c = 0; c < CH; ++c) swc[c] = lw[idc[c]];
            #pragma unroll
            for (int c = 0; c < CH; ++c) {
                float rem = m0W - cum;
                float contrib = fminf(fmaxf(rem, 0.f), swc[c]);
                acc += contrib * d2c[c];
                cum += swc[c];
            }
            if (cum >= m0W) break;   // all later contribs are exactly 0
        }
        fv_g[prob * N + i] = sqrtf(fmaxf(acc / m0W, 1e-12f));
    }
}

// ============================================================
// K3: stable argsort of f + ordered edge list (packed v|(nb<<16)),
// padded to MEDGE with inert (0,0) edges. Also vmax per problem.
// ============================================================
__global__ __launch_bounds__(512) void sort_edges_kernel(
        const float* __restrict__ fv_g,
        unsigned* __restrict__ ev32_g,
        int* __restrict__ vmax_g) {
    __shared__ float skey[NPAD];
    __shared__ short sidx_s[NPAD];
    __shared__ short rank_[N];
    __shared__ int tcnt[512];
    const int prob = blockIdx.x, tid = threadIdx.x;
    for (int j = tid; j < NPAD; j += 512) {
        skey[j]  = (j < N) ? fv_g[prob * N + j] : 3.0e38f;
        sidx_s[j] = (short)j;
    }
    __syncthreads();
    for (int k = 2; k <= NPAD; k <<= 1) {
        for (int j = k >> 1; j > 0; j >>= 1) {
            for (int a = tid; a < NPAD; a += 512) {
                int b2 = a ^ j;
                if (b2 > a) {
                    float ka = skey[a], kb = skey[b2];
                    short ia = sidx_s[a], ib = sidx_s[b2];
                    bool gt = (ka > kb) || (ka == kb && ia > ib);
                    if (gt == ((a & k) == 0)) {
                        skey[a] = kb; skey[b2] = ka;
                        sidx_s[a] = ib; sidx_s[b2] = ia;
                    }
                }
            }
            __syncthreads();
        }
    }
    for (int j = tid; j < N; j += 512) rank_[sidx_s[j]] = (short)j;
    __syncthreads();
    int cnt = 0;
    #pragma unroll
    for (int rr2 = 0; rr2 < 2; ++rr2) {
        int r = tid * 2 + rr2;
        if (r < N) {
            int v = sidx_s[r];
            int row = v / H, col = v % H;
            if (row > 0     && (int)rank_[v - H] < r) cnt++;
            if (row < H - 1 && (int)rank_[v + H] < r) cnt++;
            if (col > 0     && (int)rank_[v - 1] < r) cnt++;
            if (col < H - 1 && (int)rank_[v + 1] < r) cnt++;
        }
    }
    tcnt[tid] = cnt;
    __syncthreads();
    for (int off = 1; off < 512; off <<= 1) {
        int v = tcnt[tid];
        int add = (tid >= off) ? tcnt[tid - off] : 0;
        __syncthreads();
        tcnt[tid] = v + add;
        __syncthreads();
    }
    const int m = tcnt[511];
    int pos = tcnt[tid] - cnt;
    #pragma unroll
    for (int rr2 = 0; rr2 < 2; ++rr2) {
        int r = tid * 2 + rr2;
        if (r < N) {
            int v = sidx_s[r];
            int row = v / H, col = v % H;
            int nbs[4] = { v - H, v + H, v - 1, v + 1 };
            bool val[4] = { row > 0, row < H - 1, col > 0, col < H - 1 };
            #pragma unroll
            for (int k4 = 0; k4 < 4; ++k4) {
                if (val[k4] && (int)rank_[nbs[k4]] < r) {
                    ev32_g[prob * MEDGE + pos] = (unsigned)v | ((unsigned)nbs[k4] << 16);
                    pos++;
                }
            }
        }
    }
    for (int j = m + tid; j < MEDGE; j += 512) ev32_g[prob * MEDGE + j] = 0u;  // inert pad
    if (tid == 0) vmax_g[prob] = (int)sidx_s[N - 1];
}

// ============================================================
// K4: wave-synchronous Kruskal. 1 wave = 1 problem, no barriers.
// Lane L owns rr entries {L + s*64} in registers; LDS rr[] is the
// gather-readable mirror. Same-wave DS ops complete in order, so
// write->read needs only compiler fences (sched_barrier).
// ============================================================
__global__ __launch_bounds__(64, 1) void kruskal_kernel(
        const float* __restrict__ fv_g,
        const unsigned* __restrict__ ev32_g,
        const int* __restrict__ vmax_g,
        short* __restrict__ pd_g) {
    __shared__ float2 rr[N];
    __shared__ short pd[N];
    const int prob = blockIdx.x, lane = threadIdx.x;
    const unsigned* ed = ev32_g + prob * MEDGE;

    float2 myrr[NSLOT];
    #pragma unroll
    for (int s = 0; s < NSLOT; ++s) {
        int j = lane + s * 64;
        if (j < N) {
            myrr[s] = make_float2(fv_g[prob * N + j], __int_as_float(j));
            rr[j] = myrr[s];
            pd[j] = (short)j;
        } else {
            myrr[s] = make_float2(3.0e38f, __int_as_float(N + lane));  // inert, never matches
        }
    }
    __builtin_amdgcn_sched_barrier(0);   // LDS init before gathers

    unsigned cur[8];
    #pragma unroll
    for (int e = 0; e < 8; ++e) cur[e] = ed[e];

    for (int bi = 0; bi < NBATCH; ++bi) {
        const int base = bi * 8;
        int va[8], na[8];
        #pragma unroll
        for (int e = 0; e < 8; ++e) { va[e] = (int)(cur[e] & 0xFFFFu); na[e] = (int)(cur[e] >> 16); }
        // gather roots (uniform addresses -> broadcast reads)
        float2 ga[8], gb[8];
        #pragma unroll
        for (int e = 0; e < 8; ++e) { ga[e] = rr[va[e]]; gb[e] = rr[na[e]]; }
        // prefetch next batch's edges (hidden under resolve)
        unsigned nxt[8];
        #pragma unroll
        for (int e = 0; e < 8; ++e) nxt[e] = (bi + 1 < NBATCH) ? ed[base + 8 + e] : 0u;
        // sequential in-register resolution (identical on all lanes)
        int L[8], W[8]; float WF[8]; bool V[8];
        #pragma unroll
        for (int e = 0; e < 8; ++e) {
            int a = __float_as_int(ga[e].y); float af = ga[e].x;
            int bb = __float_as_int(gb[e].y); float bf = gb[e].x;
            #pragma unroll
            for (int j = 0; j < e; ++j) {
                bool ha = V[j] && (a == L[j]);
                a  = ha ? W[j]  : a;
                af = ha ? WF[j] : af;
                bool hb = V[j] && (bb == L[j]);
                bb = hb ? W[j]  : bb;
                bf = hb ? WF[j] : bf;
            }
            bool nw = (bf < af) || (bf == af && bb < a);
            V[e]  = (a != bb);
            W[e]  = nw ? bb : a;
            L[e]  = nw ? a  : bb;
            WF[e] = nw ? bf : af;
        }
        bool any = false;
        #pragma unroll
        for (int e = 0; e < 8; ++e) any |= V[e];
        if (__builtin_amdgcn_readfirstlane((int)any)) {   // scalar uniform branch
            // relabel register-resident slots, per actual merge only
            #pragma unroll
            for (int e = 0; e < 8; ++e) {
                if (__builtin_amdgcn_readfirstlane((int)V[e])) {
                    #pragma unroll
                    for (int s = 0; s < NSLOT; ++s) {
                        bool hit = (__float_as_int(myrr[s].y) == L[e]);
                        myrr[s].y = hit ? __int_as_float(W[e]) : myrr[s].y;
                        myrr[s].x = hit ? WF[e] : myrr[s].x;
                    }
                }
            }
            if (lane == 0) {
                #pragma unroll
                for (int e = 0; e < 8; ++e)
                    if (V[e]) pd[L[e]] = (short)va[e];
            }
            __builtin_amdgcn_sched_barrier(0);   // gathers of this batch done before writes
            #pragma unroll
            for (int s = 0; s < NSLOT; ++s) {
                int j = lane + s * 64;
                if (j < N) rr[j] = myrr[s];
            }
            __builtin_amdgcn_sched_barrier(0);   // writes before next batch's gathers
        }
        #pragma unroll
        for (int e = 0; e < 8; ++e) cur[e] = nxt[e];
    }
    __builtin_amdgcn_sched_barrier(0);
    if (lane == 0) {
        int vmax = vmax_g[prob];
        int g = __float_as_int(rr[vmax].y);
        pd[g] = (short)vmax;
    }
    __builtin_amdgcn_sched_barrier(0);
    #pragma unroll
    for (int s = 0; s < NSLOT; ++s) {
        int j = lane + s * 64;
        if (j < N) pd_g[prob * N + j] = pd[j];
    }
}

// ============================================================
// K5: landscapes top-2 per t.
// ============================================================
__global__ __launch_bounds__(256) void land_kernel(
        const float* __restrict__ fv_g,
        const short* __restrict__ pd_g,
        float* __restrict__ feat) {
    __shared__ float fv[N];
    __shared__ short pd[N];
    const int prob = blockIdx.x, tid = threadIdx.x;
    for (int j = tid; j < N; j += 256) { fv[j] = fv_g[prob * N + j]; pd[j] = pd_g[prob * N + j]; }
    __syncthreads();
    const int wave = tid >> 6, lane = tid & 63;
    for (int t = wave; t < T; t += 4) {
        float tval = (t == T - 1) ? 80.0f : (1.0f + (float)t * (79.0f / 24.0f));
        float m1 = 0.f, m2 = 0.f;
        for (int i = lane; i < N; i += 64) {
            float bi = fv[i];
            float di = fv[(int)pd[i]];
            float tv = fminf(tval - bi, di - tval);
            tv = fmaxf(tv, 0.f);
            float lo = fminf(tv, m1);
            m1 = fmaxf(tv, m1);
            m2 = fmaxf(m2, lo);
        }
        #pragma unroll
        for (int off = 32; off > 0; off >>= 1) {
            float o1 = __shfl_down(m1, off, 64);
            float o2 = __shfl_down(m2, off, 64);
            float hi = fmaxf(m1, o1);
            float lo = fminf(m1, o1);
            m2 = fmaxf(fmaxf(m2, o2), lo);
            m1 = hi;
        }
        if (lane == 0) {
            feat[prob * 50 + t]     = m1;
            feat[prob * 50 + T + t] = m2;
        }
    }
}

// ============================================================
// K6: head.
// ============================================================
__global__ void head_kernel(const float* __restrict__ feat,
                            const float* __restrict__ wg1, const float* __restrict__ bg1,
                            const float* __restrict__ wg2, const float* __restrict__ bg2,
                            const float* __restrict__ fcw, const float* __restrict__ fcb,
                            float* __restrict__ out) {
    __shared__ float xc[B * 100];
    const int tid = threadIdx.x;
    for (int e = tid; e < B * 100; e += 256) {
        int b = e / 100, j = e % 100;
        const float* fp; const float* wrow; float bias;
        if (j < 50) { fp = feat + b * 50;       wrow = wg1 + j * 50;        bias = bg1[j]; }
        else        { fp = feat + (B + b) * 50; wrow = wg2 + (j - 50) * 50; bias = bg2[j - 50]; }
        float acc = bias;
        for (int q = 0; q < 50; ++q) acc += fp[q] * wrow[q];
        xc[e] = acc;
    }
    __syncthreads();
    for (int j = tid; j < 100; j += 256) {
        float s = 0.f;
        for (int b = 0; b < B; ++b) s += fabsf(xc[b * 100 + j]);
        out[320 + j] = s;
    }
    for (int e = tid; e < 320; e += 256) {
        int b = e / 10, o = e % 10;
        float acc = fcb[o];
        for (int j = 0; j < 100; ++j)
            acc += fmaxf(xc[b * 100 + j], 0.f) * fcw[o * 100 + j];
        out[e] = acc;
    }
}

extern "C" void kernel_launch(void* const* d_in, const int* in_sizes, int n_in,
                              void* d_out, int out_size, void* d_ws, size_t ws_size,
                              hipStream_t stream) {
    (void)in_sizes; (void)n_in; (void)out_size; (void)ws_size;
    const float* x   = (const float*)d_in[0];
    const float* wg1 = (const float*)d_in[1];
    const float* bg1 = (const float*)d_in[2];
    const float* wg2 = (const float*)d_in[3];
    const float* bg2 = (const float*)d_in[4];
    const float* fcw = (const float*)d_in[5];
    const float* fcb = (const float*)d_in[6];
    float* out = (float*)d_out;

    char* ws = (char*)d_ws;
    float*          d2s   = (float*)ws;                                  // [0, 2.458M)
    unsigned short* sidxt = (unsigned short*)(ws + (size_t)N * N * 4);   // [2.458M, 3.688M)
    float*          fv_g  = (float*)(ws + (size_t)N * N * 6);            // 64*784 f32 (live across)
    unsigned*       ev32  = (unsigned*)ws;                               // 64*1536 u32 (overwrites d2s)
    short*          pd_g  = (short*)(ws + 1600 * 1024);                  // 64*784 i16
    int*            vmaxg = (int*)(ws + 2000 * 1024);                    // 64 i32
    float*          feat  = (float*)(ws + 2100 * 1024);                  // 64*50 f32

    sort_d2_kernel<<<dim3(N), dim3(256), 0, stream>>>(d2s, sidxt);
    dtm_kernel<<<dim3(64), dim3(1024), 0, stream>>>(x, d2s, sidxt, fv_g);
    sort_edges_kernel<<<dim3(64), dim3(512), 0, stream>>>(fv_g, ev32, vmaxg);
    kruskal_kernel<<<dim3(64), dim3(64), 0, stream>>>(fv_g, ev32, vmaxg, pd_g);
    land_kernel<<<dim3(64), dim3(256), 0, stream>>>(fv_g, pd_g, feat);
    head_kernel<<<dim3(1), dim3(256), 0, stream>>>(feat, wg1, bg1, wg2, bg2, fcw, fcb, out);
}

// Round 6
// 301.240 us; speedup vs baseline: 1.7467x; 1.7467x over previous
//
#include <hip/hip_runtime.h>
#include <math.h>

#define H 28
#define N 784
#define B 32
#define T 25
#define NPAD 1024
#define CH 16
#define MEDGE 1536
#define NCHUNK 24   // MEDGE / 64
#define NSLOT 13    // ceil(784/64)

// ---- numpy linspace replication (float64) ----
__device__ __forceinline__ double coord_r(int i) {
    if (i == H - 1) return 0.0;
    return 224.0 + (double)i * ((0.0 - 224.0) / 27.0);
}
__device__ __forceinline__ double coord_c(int j) {
    if (j == H - 1) return 224.0;
    return (double)j * (224.0 / 27.0);
}

// ============================================================
// K1: per-row sort by u32 key (int_d2<<10 | j).
// ============================================================
__global__ void sort_d2_kernel(float* __restrict__ d2s_t,
                               unsigned short* __restrict__ sidx_t) {
    __shared__ unsigned key[NPAD];
    const int i = blockIdx.x, tid = threadIdx.x;
    const int ri = i / H, ci = i % H;
    for (int j = tid; j < NPAD; j += 256) {
        if (j < N) {
            int dr = ri - j / H, dc = ci - j % H;
            key[j] = ((unsigned)(dr * dr + dc * dc) << 10) | (unsigned)j;
        } else {
            key[j] = 0xFFFFFFFFu;
        }
    }
    __syncthreads();
    for (int k = 2; k <= NPAD; k <<= 1) {
        for (int j = k >> 1; j > 0; j >>= 1) {
            for (int a = tid; a < NPAD; a += 256) {
                int b = a ^ j;
                if (b > a) {
                    unsigned ka = key[a], kb = key[b];
                    if ((ka > kb) == ((a & k) == 0)) { key[a] = kb; key[b] = ka; }
                }
            }
            __syncthreads();
        }
    }
    const double rri = coord_r(ri), cci = coord_c(ci);
    for (int j = tid; j < N; j += 256) {
        int jj = (int)(key[j] & 1023u);
        double dr = rri - coord_r(jj / H);
        double dc = cci - coord_c(jj % H);
        d2s_t[j * N + i]  = (float)(dr * dr + dc * dc);
        sidx_t[j * N + i] = (unsigned short)jj;
    }
}

// ============================================================
// K2: DTM. 1024 threads, one sorted-walk per thread, early exit.
// ============================================================
__global__ __launch_bounds__(1024) void dtm_kernel(
        const float* __restrict__ x,
        const float* __restrict__ d2s_t,
        const unsigned short* __restrict__ sidx_t,
        float* __restrict__ fv_g) {
    __shared__ float lw[N];
    __shared__ float red[1024];
    const int prob = blockIdx.x;
    const int b  = prob & 31;
    const int mi = prob >> 5;
    const float m0 = mi ? 0.2f : 0.05f;
    const int tid = threadIdx.x;
    float s = 0.f;
    if (tid < N) { float v = x[b * N + tid]; lw[tid] = v; s = v; }
    red[tid] = s;
    __syncthreads();
    for (int off = 512; off > 0; off >>= 1) {
        if (tid < off) red[tid] += red[tid + off];
        __syncthreads();
    }
    const float m0W = m0 * red[0];
    if (tid < N) {
        const int i = tid;
        float cum = 0.f, acc = 0.f;
        for (int k0 = 0; k0 < N; k0 += CH) {
            float d2c[CH]; int idc[CH];
            #pragma unroll
            for (int c = 0; c < CH; ++c) {
                d2c[c] = d2s_t[(k0 + c) * N + i];
                idc[c] = sidx_t[(k0 + c) * N + i];
            }
            float swc[CH];
            #pragma unroll
            for (int c = 0; c < CH; ++c) swc[c] = lw[idc[c]];
            #pragma unroll
            for (int c = 0; c < CH; ++c) {
                float rem = m0W - cum;
                float contrib = fminf(fmaxf(rem, 0.f), swc[c]);
                acc += contrib * d2c[c];
                cum += swc[c];
            }
            if (cum >= m0W) break;   // all later contribs are exactly 0
        }
        fv_g[prob * N + i] = sqrtf(fmaxf(acc / m0W, 1e-12f));
    }
}

// ============================================================
// K3: stable argsort of f + ordered edge list (packed v|(nb<<16)),
// padded to MEDGE with inert (0,0) edges. Also vmax per problem.
// ============================================================
__global__ __launch_bounds__(512) void sort_edges_kernel(
        const float* __restrict__ fv_g,
        unsigned* __restrict__ ev32_g,
        int* __restrict__ vmax_g) {
    __shared__ float skey[NPAD];
    __shared__ short sidx_s[NPAD];
    __shared__ short rank_[N];
    __shared__ int tcnt[512];
    const int prob = blockIdx.x, tid = threadIdx.x;
    for (int j = tid; j < NPAD; j += 512) {
        skey[j]  = (j < N) ? fv_g[prob * N + j] : 3.0e38f;
        sidx_s[j] = (short)j;
    }
    __syncthreads();
    for (int k = 2; k <= NPAD; k <<= 1) {
        for (int j = k >> 1; j > 0; j >>= 1) {
            for (int a = tid; a < NPAD; a += 512) {
                int b2 = a ^ j;
                if (b2 > a) {
                    float ka = skey[a], kb = skey[b2];
                    short ia = sidx_s[a], ib = sidx_s[b2];
                    bool gt = (ka > kb) || (ka == kb && ia > ib);
                    if (gt == ((a & k) == 0)) {
                        skey[a] = kb; skey[b2] = ka;
                        sidx_s[a] = ib; sidx_s[b2] = ia;
                    }
                }
            }
            __syncthreads();
        }
    }
    for (int j = tid; j < N; j += 512) rank_[sidx_s[j]] = (short)j;
    __syncthreads();
    int cnt = 0;
    #pragma unroll
    for (int rr2 = 0; rr2 < 2; ++rr2) {
        int r = tid * 2 + rr2;
        if (r < N) {
            int v = sidx_s[r];
            int row = v / H, col = v % H;
            if (row > 0     && (int)rank_[v - H] < r) cnt++;
            if (row < H - 1 && (int)rank_[v + H] < r) cnt++;
            if (col > 0     && (int)rank_[v - 1] < r) cnt++;
            if (col < H - 1 && (int)rank_[v + 1] < r) cnt++;
        }
    }
    tcnt[tid] = cnt;
    __syncthreads();
    for (int off = 1; off < 512; off <<= 1) {
        int v = tcnt[tid];
        int add = (tid >= off) ? tcnt[tid - off] : 0;
        __syncthreads();
        tcnt[tid] = v + add;
        __syncthreads();
    }
    const int m = tcnt[511];
    int pos = tcnt[tid] - cnt;
    #pragma unroll
    for (int rr2 = 0; rr2 < 2; ++rr2) {
        int r = tid * 2 + rr2;
        if (r < N) {
            int v = sidx_s[r];
            int row = v / H, col = v % H;
            int nbs[4] = { v - H, v + H, v - 1, v + 1 };
            bool val[4] = { row > 0, row < H - 1, col > 0, col < H - 1 };
            #pragma unroll
            for (int k4 = 0; k4 < 4; ++k4) {
                if (val[k4] && (int)rank_[nbs[k4]] < r) {
                    ev32_g[prob * MEDGE + pos] = (unsigned)v | ((unsigned)nbs[k4] << 16);
                    pos++;
                }
            }
        }
    }
    for (int j = m + tid; j < MEDGE; j += 512) ev32_g[prob * MEDGE + j] = 0u;  // inert pad
    if (tid == 0) vmax_g[prob] = (int)sidx_s[N - 1];
}

// ============================================================
// K4: wave-parallel Kruskal. 1 wave = 1 problem.
// pf[x] = (f[parent(x)] bits-as-float, parent(x) as int-bits).
// Chunk of 64 edges: all lanes find their roots in parallel,
// then a 64-step scalar broadcast loop resolves in exact order.
// All f comparisons are unsigned-int compares of positive-float
// bits == exact float compares.
// ============================================================
__device__ __forceinline__ int pf_find(volatile float2* pf, int x, unsigned& fbits) {
    float2 e;
    e.x = pf[x].x; e.y = pf[x].y;
    int p = __float_as_int(e.y);
    while (p != x) {
        float2 ep;
        ep.x = pf[p].x; ep.y = pf[p].y;
        int gp = __float_as_int(ep.y);
        if (gp != p) { pf[x].x = ep.x; pf[x].y = ep.y; }   // path halving
        x = p; e = ep; p = gp;
    }
    fbits = __float_as_uint(e.x);
    return x;
}

__global__ __launch_bounds__(64) void kruskal_kernel(
        const float* __restrict__ fv_g,
        const unsigned* __restrict__ ev32_g,
        const int* __restrict__ vmax_g,
        short* __restrict__ pd_g) {
    __shared__ float2 pf_s[N];
    __shared__ short pd[N];
    volatile float2* pf = pf_s;
    const int prob = blockIdx.x, lane = threadIdx.x;
    const unsigned* ed = ev32_g + prob * MEDGE;

    #pragma unroll
    for (int s = 0; s < NSLOT; ++s) {
        int j = lane + s * 64;
        if (j < N) {
            pf_s[j] = make_float2(fv_g[prob * N + j], __int_as_float(j));
            pd[j] = (short)j;
        }
    }
    __builtin_amdgcn_sched_barrier(0);   // LDS init before first finds

    unsigned cur = ed[lane];
    for (int c = 0; c < NCHUNK; ++c) {
        unsigned nxt = (c + 1 < NCHUNK) ? ed[(c + 1) * 64 + lane] : 0u;
        const int vv = (int)(cur & 0xFFFFu);
        const int nb = (int)(cur >> 16);
        unsigned fa, fb;
        int ra = pf_find(pf, vv, fa);
        int rb = pf_find(pf, nb, fb);
        // 64-step scalar broadcast resolution (exact sequential order)
        for (int j = 0; j < 64; ++j) {
            int s_a = __builtin_amdgcn_readlane(ra, j);
            int s_b = __builtin_amdgcn_readlane(rb, j);
            if (s_a != s_b) {       // uniform branch
                unsigned s_fa = (unsigned)__builtin_amdgcn_readlane((int)fa, j);
                unsigned s_fb = (unsigned)__builtin_amdgcn_readlane((int)fb, j);
                bool nw = (s_fb < s_fa) || (s_fb == s_fa && s_b < s_a);
                int s_w = nw ? s_b : s_a;
                int s_l = nw ? s_a : s_b;
                unsigned s_wf = nw ? s_fb : s_fa;
                int s_v = __builtin_amdgcn_readlane(vv, j);
                if (lane == 0) {
                    pd[s_l] = (short)s_v;
                    pf[s_l].x = __uint_as_float(s_wf);
                    pf[s_l].y = __int_as_float(s_w);
                }
                bool ha = (ra == s_l);
                ra = ha ? s_w : ra; fa = ha ? s_wf : fa;
                bool hb = (rb == s_l);
                rb = hb ? s_w : rb; fb = hb ? s_wf : fb;
            }
        }
        __builtin_amdgcn_sched_barrier(0);   // chunk writes before next finds
        cur = nxt;
    }
    if (lane == 0) {
        unsigned dummy;
        int vmax = vmax_g[prob];
        int g = pf_find(pf, vmax, dummy);
        pd[g] = (short)vmax;
    }
    __builtin_amdgcn_sched_barrier(0);
    #pragma unroll
    for (int s = 0; s < NSLOT; ++s) {
        int j = lane + s * 64;
        if (j < N) pd_g[prob * N + j] = pd[j];
    }
}

// ============================================================
// K5: landscapes top-2 per t.
// ============================================================
__global__ __launch_bounds__(256) void land_kernel(
        const float* __restrict__ fv_g,
        const short* __restrict__ pd_g,
        float* __restrict__ feat) {
    __shared__ float fv[N];
    __shared__ short pd[N];
    const int prob = blockIdx.x, tid = threadIdx.x;
    for (int j = tid; j < N; j += 256) { fv[j] = fv_g[prob * N + j]; pd[j] = pd_g[prob * N + j]; }
    __syncthreads();
    const int wave = tid >> 6, lane = tid & 63;
    for (int t = wave; t < T; t += 4) {
        float tval = (t == T - 1) ? 80.0f : (1.0f + (float)t * (79.0f / 24.0f));
        float m1 = 0.f, m2 = 0.f;
        for (int i = lane; i < N; i += 64) {
            float bi = fv[i];
            float di = fv[(int)pd[i]];
            float tv = fminf(tval - bi, di - tval);
            tv = fmaxf(tv, 0.f);
            float lo = fminf(tv, m1);
            m1 = fmaxf(tv, m1);
            m2 = fmaxf(m2, lo);
        }
        #pragma unroll
        for (int off = 32; off > 0; off >>= 1) {
            float o1 = __shfl_down(m1, off, 64);
            float o2 = __shfl_down(m2, off, 64);
            float hi = fmaxf(m1, o1);
            float lo = fminf(m1, o1);
            m2 = fmaxf(fmaxf(m2, o2), lo);
            m1 = hi;
        }
        if (lane == 0) {
            feat[prob * 50 + t]     = m1;
            feat[prob * 50 + T + t] = m2;
        }
    }
}

// ============================================================
// K6: head.
// ============================================================
__global__ void head_kernel(const float* __restrict__ feat,
                            const float* __restrict__ wg1, const float* __restrict__ bg1,
                            const float* __restrict__ wg2, const float* __restrict__ bg2,
                            const float* __restrict__ fcw, const float* __restrict__ fcb,
                            float* __restrict__ out) {
    __shared__ float xc[B * 100];
    const int tid = threadIdx.x;
    for (int e = tid; e < B * 100; e += 256) {
        int b = e / 100, j = e % 100;
        const float* fp; const float* wrow; float bias;
        if (j < 50) { fp = feat + b * 50;       wrow = wg1 + j * 50;        bias = bg1[j]; }
        else        { fp = feat + (B + b) * 50; wrow = wg2 + (j - 50) * 50; bias = bg2[j - 50]; }
        float acc = bias;
        for (int q = 0; q < 50; ++q) acc += fp[q] * wrow[q];
        xc[e] = acc;
    }
    __syncthreads();
    for (int j = tid; j < 100; j += 256) {
        float s = 0.f;
        for (int b = 0; b < B; ++b) s += fabsf(xc[b * 100 + j]);
        out[320 + j] = s;
    }
    for (int e = tid; e < 320; e += 256) {
        int b = e / 10, o = e % 10;
        float acc = fcb[o];
        for (int j = 0; j < 100; ++j)
            acc += fmaxf(xc[b * 100 + j], 0.f) * fcw[o * 100 + j];
        out[e] = acc;
    }
}

extern "C" void kernel_launch(void* const* d_in, const int* in_sizes, int n_in,
                              void* d_out, int out_size, void* d_ws, size_t ws_size,
                              hipStream_t stream) {
    (void)in_sizes; (void)n_in; (void)out_size; (void)ws_size;
    const float* x   = (const float*)d_in[0];
    const float* wg1 = (const float*)d_in[1];
    const float* bg1 = (const float*)d_in[2];
    const float* wg2 = (const float*)d_in[3];
    const float* bg2 = (const float*)d_in[4];
    const float* fcw = (const float*)d_in[5];
    const float* fcb = (const float*)d_in[6];
    float* out = (float*)d_out;

    char* ws = (char*)d_ws;
    float*          d2s   = (float*)ws;                                  // [0, 2.458M)
    unsigned short* sidxt = (unsigned short*)(ws + (size_t)N * N * 4);   // [2.458M, 3.688M)
    float*          fv_g  = (float*)(ws + (size_t)N * N * 6);            // 64*784 f32 (live across)
    unsigned*       ev32  = (unsigned*)ws;                               // 64*1536 u32 (overwrites d2s)
    short*          pd_g  = (short*)(ws + 1600 * 1024);                  // 64*784 i16
    int*            vmaxg = (int*)(ws + 2000 * 1024);                    // 64 i32
    float*          feat  = (float*)(ws + 2100 * 1024);                  // 64*50 f32

    sort_d2_kernel<<<dim3(N), dim3(256), 0, stream>>>(d2s, sidxt);
    dtm_kernel<<<dim3(64), dim3(1024), 0, stream>>>(x, d2s, sidxt, fv_g);
    sort_edges_kernel<<<dim3(64), dim3(512), 0, stream>>>(fv_g, ev32, vmaxg);
    kruskal_kernel<<<dim3(64), dim3(64), 0, stream>>>(fv_g, ev32, vmaxg, pd_g);
    land_kernel<<<dim3(64), dim3(256), 0, stream>>>(fv_g, pd_g, feat);
    head_kernel<<<dim3(1), dim3(256), 0, stream>>>(feat, wg1, bg1, wg2, bg2, fcw, fcb, out);
}

// Round 7
// 236.343 us; speedup vs baseline: 2.2264x; 1.2746x over previous
//
#include <hip/hip_runtime.h>
#include <math.h>

#define H 28
#define N 784
#define B 32
#define T 25
#define NPAD 1024
#define CH 16
#define MEDGE 1536
#define NCHUNK 24   // MEDGE / 64

// ---- numpy linspace replication (float64) ----
__device__ __forceinline__ double coord_r(int i) {
    if (i == H - 1) return 0.0;
    return 224.0 + (double)i * ((0.0 - 224.0) / 27.0);
}
__device__ __forceinline__ double coord_c(int j) {
    if (j == H - 1) return 224.0;
    return (double)j * (224.0 / 27.0);
}

// ============================================================
// K1: per-row sort by u32 key (int_d2<<10 | j).
// ============================================================
__global__ void sort_d2_kernel(float* __restrict__ d2s_t,
                               unsigned short* __restrict__ sidx_t) {
    __shared__ unsigned key[NPAD];
    const int i = blockIdx.x, tid = threadIdx.x;
    const int ri = i / H, ci = i % H;
    for (int j = tid; j < NPAD; j += 256) {
        if (j < N) {
            int dr = ri - j / H, dc = ci - j % H;
            key[j] = ((unsigned)(dr * dr + dc * dc) << 10) | (unsigned)j;
        } else {
            key[j] = 0xFFFFFFFFu;
        }
    }
    __syncthreads();
    for (int k = 2; k <= NPAD; k <<= 1) {
        for (int j = k >> 1; j > 0; j >>= 1) {
            for (int a = tid; a < NPAD; a += 256) {
                int b = a ^ j;
                if (b > a) {
                    unsigned ka = key[a], kb = key[b];
                    if ((ka > kb) == ((a & k) == 0)) { key[a] = kb; key[b] = ka; }
                }
            }
            __syncthreads();
        }
    }
    const double rri = coord_r(ri), cci = coord_c(ci);
    for (int j = tid; j < N; j += 256) {
        int jj = (int)(key[j] & 1023u);
        double dr = rri - coord_r(jj / H);
        double dc = cci - coord_c(jj % H);
        d2s_t[j * N + i]  = (float)(dr * dr + dc * dc);
        sidx_t[j * N + i] = (unsigned short)jj;
    }
}

// ============================================================
// K2: DTM. 1024 threads, one sorted-walk per thread, early exit.
// ============================================================
__global__ __launch_bounds__(1024) void dtm_kernel(
        const float* __restrict__ x,
        const float* __restrict__ d2s_t,
        const unsigned short* __restrict__ sidx_t,
        float* __restrict__ fv_g) {
    __shared__ float lw[N];
    __shared__ float red[1024];
    const int prob = blockIdx.x;
    const int b  = prob & 31;
    const int mi = prob >> 5;
    const float m0 = mi ? 0.2f : 0.05f;
    const int tid = threadIdx.x;
    float s = 0.f;
    if (tid < N) { float v = x[b * N + tid]; lw[tid] = v; s = v; }
    red[tid] = s;
    __syncthreads();
    for (int off = 512; off > 0; off >>= 1) {
        if (tid < off) red[tid] += red[tid + off];
        __syncthreads();
    }
    const float m0W = m0 * red[0];
    if (tid < N) {
        const int i = tid;
        float cum = 0.f, acc = 0.f;
        for (int k0 = 0; k0 < N; k0 += CH) {
            float d2c[CH]; int idc[CH];
            #pragma unroll
            for (int c = 0; c < CH; ++c) {
                d2c[c] = d2s_t[(k0 + c) * N + i];
                idc[c] = sidx_t[(k0 + c) * N + i];
            }
            float swc[CH];
            #pragma unroll
            for (int c = 0; c < CH; ++c) swc[c] = lw[idc[c]];
            #pragma unroll
            for (int c = 0; c < CH; ++c) {
                float rem = m0W - cum;
                float contrib = fminf(fmaxf(rem, 0.f), swc[c]);
                acc += contrib * d2c[c];
                cum += swc[c];
            }
            if (cum >= m0W) break;   // all later contribs are exactly 0
        }
        fv_g[prob * N + i] = sqrtf(fmaxf(acc / m0W, 1e-12f));
    }
}

// ============================================================
// K3 (fused): argsort + edge list + wave-0 Kruskal + landscapes.
// One 512-thread block per (m0, b) problem.
// ============================================================
__device__ __forceinline__ int pf_find(volatile float2* pf, int x, unsigned& fbits) {
    float2 e;
    e.x = pf[x].x; e.y = pf[x].y;
    int p = __float_as_int(e.y);
    while (p != x) {
        float2 ep;
        ep.x = pf[p].x; ep.y = pf[p].y;
        int gp = __float_as_int(ep.y);
        if (gp != p) { pf[x].x = ep.x; pf[x].y = ep.y; }   // path halving
        x = p; e = ep; p = gp;
    }
    fbits = __float_as_uint(e.x);
    return x;
}

__global__ __launch_bounds__(512) void topo_kernel(
        const float* __restrict__ fv_g,
        float* __restrict__ feat) {
    __shared__ float skey[NPAD];
    __shared__ short sidx_s[NPAD];
    __shared__ short rank_[N];
    __shared__ int tcnt[512];
    __shared__ float fv[N];
    __shared__ float2 pf_s[N];
    __shared__ short pd[N];
    __shared__ unsigned ev[MEDGE];
    volatile float2* pf = pf_s;

    const int prob = blockIdx.x, tid = threadIdx.x;

    // ---- load f, init sort arrays ----
    for (int j = tid; j < NPAD; j += 512) {
        float v = (j < N) ? fv_g[prob * N + j] : 3.0e38f;
        skey[j] = v;
        sidx_s[j] = (short)j;
        if (j < N) fv[j] = v;
    }
    __syncthreads();
    // ---- stable bitonic argsort ascending by (f, idx) ----
    for (int k = 2; k <= NPAD; k <<= 1) {
        for (int j = k >> 1; j > 0; j >>= 1) {
            for (int a = tid; a < NPAD; a += 512) {
                int b2 = a ^ j;
                if (b2 > a) {
                    float ka = skey[a], kb = skey[b2];
                    short ia = sidx_s[a], ib = sidx_s[b2];
                    bool gt = (ka > kb) || (ka == kb && ia > ib);
                    if (gt == ((a & k) == 0)) {
                        skey[a] = kb; skey[b2] = ka;
                        sidx_s[a] = ib; sidx_s[b2] = ia;
                    }
                }
            }
            __syncthreads();
        }
    }
    // ---- rank, pf, pd init ----
    for (int j = tid; j < N; j += 512) {
        rank_[sidx_s[j]] = (short)j;
        pf_s[j] = make_float2(fv[j], __int_as_float(j));
        pd[j] = (short)j;
    }
    __syncthreads();
    // ---- ordered edge list (rank of later endpoint, nbr slot) ----
    int cnt = 0;
    {
        int r = tid;
        if (r < N) {
            int v = sidx_s[r];
            int row = v / H, col = v % H;
            if (row > 0     && (int)rank_[v - H] < r) cnt++;
            if (row < H - 1 && (int)rank_[v + H] < r) cnt++;
            if (col > 0     && (int)rank_[v - 1] < r) cnt++;
            if (col < H - 1 && (int)rank_[v + 1] < r) cnt++;
        }
        int r2 = tid + 512;
        if (r2 < N) {
            int v = sidx_s[r2];
            int row = v / H, col = v % H;
            if (row > 0     && (int)rank_[v - H] < r2) cnt++;
            if (row < H - 1 && (int)rank_[v + H] < r2) cnt++;
            if (col > 0     && (int)rank_[v - 1] < r2) cnt++;
            if (col < H - 1 && (int)rank_[v + 1] < r2) cnt++;
        }
    }
    tcnt[tid] = cnt;
    __syncthreads();
    for (int off = 1; off < 512; off <<= 1) {
        int v = tcnt[tid];
        int add = (tid >= off) ? tcnt[tid - off] : 0;
        __syncthreads();
        tcnt[tid] = v + add;
        __syncthreads();
    }
    const int m = tcnt[511];
    // NOTE: tid's edges (ranks tid and tid+512) are contiguous in the
    // prefix order ONLY if we scatter rank tid's edges first and rank
    // tid+512's after all of rank tid's... they are not adjacent.
    // Recompute per-rank offsets: rank r=tid gets offset (tcnt[tid]-cnt);
    // rank tid+512's edges follow all edges of ranks < tid+512, i.e.
    // they sit after tcnt[511]-(edges of ranks >= 512 before tid+512)...
    // Simplest correct: redo scan per half.
    __syncthreads();
    {
        // count for rank tid only
        int c1 = 0;
        if (tid < N) {
            int v = sidx_s[tid];
            int row = v / H, col = v % H;
            if (row > 0     && (int)rank_[v - H] < tid) c1++;
            if (row < H - 1 && (int)rank_[v + H] < tid) c1++;
            if (col > 0     && (int)rank_[v - 1] < tid) c1++;
            if (col < H - 1 && (int)rank_[v + 1] < tid) c1++;
        }
        tcnt[tid] = c1;
        __syncthreads();
        for (int off = 1; off < 512; off <<= 1) {
            int v = tcnt[tid];
            int add = (tid >= off) ? tcnt[tid - off] : 0;
            __syncthreads();
            tcnt[tid] = v + add;
            __syncthreads();
        }
        int half1_total = tcnt[511];
        // scatter rank tid
        if (tid < N) {
            int pos = tcnt[tid] - c1;
            int v = sidx_s[tid];
            int row = v / H, col = v % H;
            int nbs[4] = { v - H, v + H, v - 1, v + 1 };
            bool val[4] = { row > 0, row < H - 1, col > 0, col < H - 1 };
            #pragma unroll
            for (int k4 = 0; k4 < 4; ++k4) {
                if (val[k4] && (int)rank_[nbs[k4]] < tid) {
                    ev[pos] = (unsigned)v | ((unsigned)nbs[k4] << 16);
                    pos++;
                }
            }
        }
        __syncthreads();
        // count for rank tid+512
        int r2 = tid + 512;
        int c2 = 0;
        if (r2 < N) {
            int v = sidx_s[r2];
            int row = v / H, col = v % H;
            if (row > 0     && (int)rank_[v - H] < r2) c2++;
            if (row < H - 1 && (int)rank_[v + H] < r2) c2++;
            if (col > 0     && (int)rank_[v - 1] < r2) c2++;
            if (col < H - 1 && (int)rank_[v + 1] < r2) c2++;
        }
        __syncthreads();
        tcnt[tid] = c2;
        __syncthreads();
        for (int off = 1; off < 512; off <<= 1) {
            int v = tcnt[tid];
            int add = (tid >= off) ? tcnt[tid - off] : 0;
            __syncthreads();
            tcnt[tid] = v + add;
            __syncthreads();
        }
        if (r2 < N) {
            int pos = half1_total + tcnt[tid] - c2;
            int v = sidx_s[r2];
            int row = v / H, col = v % H;
            int nbs[4] = { v - H, v + H, v - 1, v + 1 };
            bool val[4] = { row > 0, row < H - 1, col > 0, col < H - 1 };
            #pragma unroll
            for (int k4 = 0; k4 < 4; ++k4) {
                if (val[k4] && (int)rank_[nbs[k4]] < r2) {
                    ev[pos] = (unsigned)v | ((unsigned)nbs[k4] << 16);
                    pos++;
                }
            }
        }
    }
    for (int j = m + tid; j < MEDGE; j += 512) ev[j] = 0u;  // inert pad
    __syncthreads();

    // ---- wave-0 Kruskal: parallel finds + register broadcast resolve ----
    if (tid < 64) {
        const int lane = tid;
        unsigned cur = ev[lane];
        for (int c = 0; c < NCHUNK; ++c) {
            unsigned nxt = (c + 1 < NCHUNK) ? ev[(c + 1) * 64 + lane] : 0u;
            const int vv = (int)(cur & 0xFFFFu);
            const int nb = (int)(cur >> 16);
            unsigned fa, fb;
            int ra = pf_find(pf, vv, fa);
            int rb = pf_find(pf, nb, fb);
            int myL = -1, myW = 0; unsigned myWF = 0;
            unsigned long long mask = __ballot(ra != rb);
            while (mask) {
                int j = __builtin_ctzll(mask);
                mask &= mask - 1;
                int s_a = __builtin_amdgcn_readlane(ra, j);
                int s_b = __builtin_amdgcn_readlane(rb, j);
                if (s_a != s_b) {          // uniform
                    unsigned s_fa = (unsigned)__builtin_amdgcn_readlane((int)fa, j);
                    unsigned s_fb = (unsigned)__builtin_amdgcn_readlane((int)fb, j);
                    bool nw = (s_fb < s_fa) || (s_fb == s_fa && s_b < s_a);
                    int s_w = nw ? s_b : s_a;
                    int s_l = nw ? s_a : s_b;
                    unsigned s_wf = nw ? s_fb : s_fa;
                    bool me = (lane == j);
                    myL  = me ? s_l  : myL;
                    myW  = me ? s_w  : myW;
                    myWF = me ? s_wf : myWF;
                    bool ha = (ra == s_l);
                    ra = ha ? s_w : ra; fa = ha ? s_wf : fa;
                    bool hb = (rb == s_l);
                    rb = hb ? s_w : rb; fb = hb ? s_wf : fb;
                }
            }
            // one parallel write round; losers distinct -> race-free
            if (myL >= 0) {
                pd[myL] = (short)vv;
                pf[myL].x = __uint_as_float(myWF);
                pf[myL].y = __int_as_float(myW);
            }
            __builtin_amdgcn_sched_barrier(0);   // writes before next finds
            cur = nxt;
        }
        if (lane == 0) {
            unsigned dummy;
            int vmax = (int)sidx_s[N - 1];
            int g = pf_find(pf, vmax, dummy);
            pd[g] = (short)vmax;
        }
    }
    __syncthreads();

    // ---- landscapes: top-2 of tent functions per t (8 waves) ----
    const int wave = tid >> 6, lane = tid & 63;
    for (int t = wave; t < T; t += 8) {
        float tval = (t == T - 1) ? 80.0f : (1.0f + (float)t * (79.0f / 24.0f));
        float m1 = 0.f, m2 = 0.f;
        for (int i = lane; i < N; i += 64) {
            float bi = fv[i];
            float di = fv[(int)pd[i]];
            float tv = fminf(tval - bi, di - tval);
            tv = fmaxf(tv, 0.f);
            float lo = fminf(tv, m1);
            m1 = fmaxf(tv, m1);
            m2 = fmaxf(m2, lo);
        }
        #pragma unroll
        for (int off = 32; off > 0; off >>= 1) {
            float o1 = __shfl_down(m1, off, 64);
            float o2 = __shfl_down(m2, off, 64);
            float hi = fmaxf(m1, o1);
            float lo = fminf(m1, o1);
            m2 = fmaxf(fmaxf(m2, o2), lo);
            m1 = hi;
        }
        if (lane == 0) {
            feat[prob * 50 + t]     = m1;
            feat[prob * 50 + T + t] = m2;
        }
    }
}

// ============================================================
// K4: head.
// ============================================================
__global__ void head_kernel(const float* __restrict__ feat,
                            const float* __restrict__ wg1, const float* __restrict__ bg1,
                            const float* __restrict__ wg2, const float* __restrict__ bg2,
                            const float* __restrict__ fcw, const float* __restrict__ fcb,
                            float* __restrict__ out) {
    __shared__ float xc[B * 100];
    const int tid = threadIdx.x;
    for (int e = tid; e < B * 100; e += 256) {
        int b = e / 100, j = e % 100;
        const float* fp; const float* wrow; float bias;
        if (j < 50) { fp = feat + b * 50;       wrow = wg1 + j * 50;        bias = bg1[j]; }
        else        { fp = feat + (B + b) * 50; wrow = wg2 + (j - 50) * 50; bias = bg2[j - 50]; }
        float acc = bias;
        for (int q = 0; q < 50; ++q) acc += fp[q] * wrow[q];
        xc[e] = acc;
    }
    __syncthreads();
    for (int j = tid; j < 100; j += 256) {
        float s = 0.f;
        for (int b = 0; b < B; ++b) s += fabsf(xc[b * 100 + j]);
        out[320 + j] = s;
    }
    for (int e = tid; e < 320; e += 256) {
        int b = e / 10, o = e % 10;
        float acc = fcb[o];
        for (int j = 0; j < 100; ++j)
            acc += fmaxf(xc[b * 100 + j], 0.f) * fcw[o * 100 + j];
        out[e] = acc;
    }
}

extern "C" void kernel_launch(void* const* d_in, const int* in_sizes, int n_in,
                              void* d_out, int out_size, void* d_ws, size_t ws_size,
                              hipStream_t stream) {
    (void)in_sizes; (void)n_in; (void)out_size; (void)ws_size;
    const float* x   = (const float*)d_in[0];
    const float* wg1 = (const float*)d_in[1];
    const float* bg1 = (const float*)d_in[2];
    const float* wg2 = (const float*)d_in[3];
    const float* bg2 = (const float*)d_in[4];
    const float* fcw = (const float*)d_in[5];
    const float* fcb = (const float*)d_in[6];
    float* out = (float*)d_out;

    char* ws = (char*)d_ws;
    float*          d2s   = (float*)ws;                                  // N*N f32
    unsigned short* sidxt = (unsigned short*)(ws + (size_t)N * N * 4);   // N*N u16
    float*          fv_g  = (float*)(ws + (size_t)N * N * 6);            // 64*784 f32
    float*          feat  = (float*)(ws + (size_t)N * N * 6 + 64 * N * 4); // 64*50 f32

    sort_d2_kernel<<<dim3(N), dim3(256), 0, stream>>>(d2s, sidxt);
    dtm_kernel<<<dim3(64), dim3(1024), 0, stream>>>(x, d2s, sidxt, fv_g);
    topo_kernel<<<dim3(64), dim3(512), 0, stream>>>(fv_g, feat);
    head_kernel<<<dim3(1), dim3(256), 0, stream>>>(feat, wg1, bg1, wg2, bg2, fcw, fcb, out);
}